// Round 1
// baseline (1269.874 us; speedup 1.0000x reference)
//
#include <hip/hip_runtime.h>

#define DIM    64
#define KCODES 4096
#define NROWS  65536
#define BLK    256
#define NBLK   (NROWS / BLK)

__device__ __forceinline__ float4 ldg4(const float* p) {
  return *reinterpret_cast<const float4*>(p);
}

__device__ __forceinline__ float4 f4add(float4 a, float4 b) {
  float4 r;
  r.x = __fadd_rn(a.x, b.x); r.y = __fadd_rn(a.y, b.y);
  r.z = __fadd_rn(a.z, b.z); r.w = __fadd_rn(a.w, b.w);
  return r;
}

__device__ __forceinline__ float4 f4sqacc(float4 acc, float4 e) {
  float4 r;
  r.x = __fadd_rn(acc.x, __fmul_rn(e.x, e.x));
  r.y = __fadd_rn(acc.y, __fmul_rn(e.y, e.y));
  r.z = __fadd_rn(acc.z, __fmul_rn(e.z, e.z));
  r.w = __fadd_rn(acc.w, __fmul_rn(e.w, e.w));
  return r;
}

// One row per thread. Distances computed to mimic f32 numpy/BLAS rounding:
//  - dot: sequential ascending-d FMA chain (sgemm order)
//  - fnorm/enorm: numpy pairwise-8 pattern, products rounded (no contraction)
//  - dist = (fnorm + enorm[k]) - 2*dot, strict-< first-index argmin
__global__ __launch_bounds__(BLK) void vq_main(
    const float* __restrict__ x, const float* __restrict__ emb,
    float* __restrict__ out, double* __restrict__ red) {
  __shared__ __align__(16) float s_en[KCODES];
  __shared__ double s_red[8];
  const int tid = threadIdx.x;
  const int row = blockIdx.x * BLK + tid;

  // ---- Phase 1: codebook column norms into LDS (numpy pairwise-8 over d) ----
  #pragma unroll
  for (int g = 0; g < 4; ++g) {
    const int k0 = 4 * tid + 1024 * g;
    float4 acc[8];
    #pragma unroll
    for (int j = 0; j < 8; ++j) {
      float4 e = ldg4(emb + j * KCODES + k0);
      acc[j].x = __fmul_rn(e.x, e.x);
      acc[j].y = __fmul_rn(e.y, e.y);
      acc[j].z = __fmul_rn(e.z, e.z);
      acc[j].w = __fmul_rn(e.w, e.w);
    }
    #pragma unroll
    for (int i = 1; i < 8; ++i) {
      #pragma unroll
      for (int j = 0; j < 8; ++j) {
        float4 e = ldg4(emb + (8 * i + j) * KCODES + k0);
        acc[j] = f4sqacc(acc[j], e);
      }
    }
    float4 s = f4add(f4add(f4add(acc[0], acc[1]), f4add(acc[2], acc[3])),
                     f4add(f4add(acc[4], acc[5]), f4add(acc[6], acc[7])));
    *reinterpret_cast<float4*>(&s_en[k0]) = s;
  }

  // ---- Phase 2: row into registers + fnorm (pairwise-8) ----
  float f[DIM];
  #pragma unroll
  for (int i = 0; i < 16; ++i) {
    float4 v = ldg4(x + row * DIM + 4 * i);
    f[4 * i + 0] = v.x; f[4 * i + 1] = v.y;
    f[4 * i + 2] = v.z; f[4 * i + 3] = v.w;
  }
  float r8[8];
  #pragma unroll
  for (int j = 0; j < 8; ++j) r8[j] = __fmul_rn(f[j], f[j]);
  #pragma unroll
  for (int i = 1; i < 8; ++i) {
    #pragma unroll
    for (int j = 0; j < 8; ++j)
      r8[j] = __fadd_rn(r8[j], __fmul_rn(f[8 * i + j], f[8 * i + j]));
  }
  const float fnorm = __fadd_rn(
      __fadd_rn(__fadd_rn(r8[0], r8[1]), __fadd_rn(r8[2], r8[3])),
      __fadd_rn(__fadd_rn(r8[4], r8[5]), __fadd_rn(r8[6], r8[7])));

  __syncthreads();

  // ---- Phase 3: argmin over all 4096 codes, 4 codes per iteration ----
  float dmin = 3.4028234663852886e38f;
  int   imin = 0;
  for (int k = 0; k < KCODES; k += 4) {
    float d0 = 0.f, d1 = 0.f, d2 = 0.f, d3 = 0.f;
    #pragma unroll
    for (int dd = 0; dd < DIM; ++dd) {
      // wave-uniform address -> scalar loads (s_load_dwordx4), sL1-resident
      const float4 e = ldg4(emb + dd * KCODES + k);
      d0 = fmaf(f[dd], e.x, d0);
      d1 = fmaf(f[dd], e.y, d1);
      d2 = fmaf(f[dd], e.z, d2);
      d3 = fmaf(f[dd], e.w, d3);
    }
    const float4 en = *reinterpret_cast<const float4*>(&s_en[k]);
    float di;
    di = __fsub_rn(__fadd_rn(fnorm, en.x), __fmul_rn(2.0f, d0));
    if (di < dmin) { dmin = di; imin = k; }
    di = __fsub_rn(__fadd_rn(fnorm, en.y), __fmul_rn(2.0f, d1));
    if (di < dmin) { dmin = di; imin = k + 1; }
    di = __fsub_rn(__fadd_rn(fnorm, en.z), __fmul_rn(2.0f, d2));
    if (di < dmin) { dmin = di; imin = k + 2; }
    di = __fsub_rn(__fadd_rn(fnorm, en.w), __fmul_rn(2.0f, d3));
    if (di < dmin) { dmin = di; imin = k + 3; }
  }

  // ---- Phase 4: gather winning code, write estimator, loss partials ----
  double s1 = 0.0, s2 = 0.0;
  #pragma unroll
  for (int dd4 = 0; dd4 < DIM; dd4 += 4) {
    float4 q;
    q.x = emb[(dd4 + 0) * KCODES + imin];
    q.y = emb[(dd4 + 1) * KCODES + imin];
    q.z = emb[(dd4 + 2) * KCODES + imin];
    q.w = emb[(dd4 + 3) * KCODES + imin];
    *reinterpret_cast<float4*>(out + row * DIM + dd4) = q;
    const float dx = __fsub_rn(q.x, f[dd4 + 0]);
    const float dy = __fsub_rn(q.y, f[dd4 + 1]);
    const float dz = __fsub_rn(q.z, f[dd4 + 2]);
    const float dw = __fsub_rn(q.w, f[dd4 + 3]);
    s1 += ((double)dx + (double)dy) + ((double)dz + (double)dw);
    s2 += ((double)dx * dx + (double)dy * dy) +
          ((double)dz * dz + (double)dw * dw);
  }

  // wave reduce (64 lanes), then block reduce, then one atomic per block
  #pragma unroll
  for (int off = 32; off > 0; off >>= 1) {
    s1 += __shfl_down(s1, off, 64);
    s2 += __shfl_down(s2, off, 64);
  }
  const int lane = tid & 63, wid = tid >> 6;
  if (lane == 0) { s_red[wid] = s1; s_red[4 + wid] = s2; }
  __syncthreads();
  if (tid == 0) {
    const double a = (s_red[0] + s_red[1]) + (s_red[2] + s_red[3]);
    const double b = (s_red[4] + s_red[5]) + (s_red[6] + s_red[7]);
    atomicAdd(&red[0], a);
    atomicAdd(&red[1], b);
  }
}

__global__ void vq_loss(const double* __restrict__ red, float* __restrict__ out) {
  const double inv = 1.0 / (double)((long long)NROWS * DIM);
  const double m1 = red[0] * inv;
  const double m2 = red[1] * inv;
  out[(long long)NROWS * DIM] = (float)(0.25 * m1 * m1 + m2);
}

extern "C" void kernel_launch(void* const* d_in, const int* in_sizes, int n_in,
                              void* d_out, int out_size, void* d_ws, size_t ws_size,
                              hipStream_t stream) {
  const float* x   = (const float*)d_in[0];
  const float* emb = (const float*)d_in[1];
  float* out = (float*)d_out;
  double* red = (double*)d_ws;
  hipMemsetAsync(d_ws, 0, 2 * sizeof(double), stream);
  vq_main<<<NBLK, BLK, 0, stream>>>(x, emb, out, red);
  vq_loss<<<1, 1, 0, stream>>>(red, out);
}

// Round 2
// 492.721 us; speedup vs baseline: 2.5773x; 2.5773x over previous
//
#include <hip/hip_runtime.h>

#define DIM     64
#define KCODES  4096
#define NROWS   65536
#define BLK     256
#define TR      64                 // rows per block
#define TC      128                // codes per LDS chunk
#define NCHUNK  (KCODES / TC)      // 32
#define NBLK    (NROWS / TR)       // 1024
#define R       8                  // rows per thread
#define C       4                  // codes per thread
#define XSTRIDE 68                 // padded [d][row] stride (16B-aligned, breaks bank aliasing)

__device__ __forceinline__ float4 ldg4(const float* p) {
  return *reinterpret_cast<const float4*>(p);
}

__device__ __forceinline__ float4 f4sqacc(float4 acc, float4 e) {
  float4 r;
  r.x = __fadd_rn(acc.x, __fmul_rn(e.x, e.x));
  r.y = __fadd_rn(acc.y, __fmul_rn(e.y, e.y));
  r.z = __fadd_rn(acc.z, __fmul_rn(e.z, e.z));
  r.w = __fadd_rn(acc.w, __fmul_rn(e.w, e.w));
  return r;
}

// ||e_k||^2 for all 4096 codes, numpy pairwise-8 order over d (validated round 0).
__global__ __launch_bounds__(BLK) void vq_enorm(const float* __restrict__ emb,
                                                float* __restrict__ en) {
  const int k0 = 4 * threadIdx.x + 1024 * blockIdx.x;
  float4 acc[8];
  #pragma unroll
  for (int j = 0; j < 8; ++j) {
    float4 e = ldg4(emb + j * KCODES + k0);
    acc[j].x = __fmul_rn(e.x, e.x); acc[j].y = __fmul_rn(e.y, e.y);
    acc[j].z = __fmul_rn(e.z, e.z); acc[j].w = __fmul_rn(e.w, e.w);
  }
  #pragma unroll
  for (int i = 1; i < 8; ++i) {
    #pragma unroll
    for (int j = 0; j < 8; ++j)
      acc[j] = f4sqacc(acc[j], ldg4(emb + (8 * i + j) * KCODES + k0));
  }
  float4 s;
  s.x = __fadd_rn(__fadd_rn(__fadd_rn(acc[0].x, acc[1].x), __fadd_rn(acc[2].x, acc[3].x)),
                  __fadd_rn(__fadd_rn(acc[4].x, acc[5].x), __fadd_rn(acc[6].x, acc[7].x)));
  s.y = __fadd_rn(__fadd_rn(__fadd_rn(acc[0].y, acc[1].y), __fadd_rn(acc[2].y, acc[3].y)),
                  __fadd_rn(__fadd_rn(acc[4].y, acc[5].y), __fadd_rn(acc[6].y, acc[7].y)));
  s.z = __fadd_rn(__fadd_rn(__fadd_rn(acc[0].z, acc[1].z), __fadd_rn(acc[2].z, acc[3].z)),
                  __fadd_rn(__fadd_rn(acc[4].z, acc[5].z), __fadd_rn(acc[6].z, acc[7].z)));
  s.w = __fadd_rn(__fadd_rn(__fadd_rn(acc[0].w, acc[1].w), __fadd_rn(acc[2].w, acc[3].w)),
                  __fadd_rn(__fadd_rn(acc[4].w, acc[5].w), __fadd_rn(acc[6].w, acc[7].w)));
  *reinterpret_cast<float4*>(&en[k0]) = s;
}

// Register-blocked f32 GEMM + exact argmin epilogue.
// Block: TR=64 rows x 4096 codes (chunks of TC=128 in LDS).
// Thread (cg=tid&31, rg=tid>>5): R=8 rows x C=4 codes accumulators; each
// acc is a single sequential fmaf chain over d (bit-identical to round 0).
__global__ __launch_bounds__(BLK) void vq_main(
    const float* __restrict__ x, const float* __restrict__ emb,
    const float* __restrict__ en, float* __restrict__ out,
    double* __restrict__ red) {
  __shared__ float  s_x[DIM * XSTRIDE];   // [d][row]
  __shared__ float  s_e[DIM * TC];        // [d][code]
  __shared__ float  s_fn[TR];
  __shared__ double s_red[8];

  const int tid = threadIdx.x;
  const int rowbase = blockIdx.x * TR;
  const int cg = tid & 31;
  const int rg = tid >> 5;

  // ---- stage x tile transposed: s_x[d][row] ----
  #pragma unroll
  for (int i = 0; i < 4; ++i) {
    const int fi = tid + i * BLK;        // float4 slot 0..1023
    const int r  = fi >> 4;              // row 0..63
    const int d4 = (fi & 15) * 4;
    const float4 v = ldg4(x + (size_t)(rowbase + r) * DIM + d4);
    s_x[(d4 + 0) * XSTRIDE + r] = v.x;
    s_x[(d4 + 1) * XSTRIDE + r] = v.y;
    s_x[(d4 + 2) * XSTRIDE + r] = v.z;
    s_x[(d4 + 3) * XSTRIDE + r] = v.w;
  }
  __syncthreads();

  // ---- fnorm per row (pairwise-8 over d, round-0 ordering) ----
  if (tid < TR) {
    float r8[8];
    #pragma unroll
    for (int j = 0; j < 8; ++j) {
      const float v = s_x[j * XSTRIDE + tid];
      r8[j] = __fmul_rn(v, v);
    }
    #pragma unroll
    for (int i = 1; i < 8; ++i) {
      #pragma unroll
      for (int j = 0; j < 8; ++j) {
        const float v = s_x[(8 * i + j) * XSTRIDE + tid];
        r8[j] = __fadd_rn(r8[j], __fmul_rn(v, v));
      }
    }
    s_fn[tid] = __fadd_rn(
        __fadd_rn(__fadd_rn(r8[0], r8[1]), __fadd_rn(r8[2], r8[3])),
        __fadd_rn(__fadd_rn(r8[4], r8[5]), __fadd_rn(r8[6], r8[7])));
  }

  float dmin[R];
  int   imin[R];
  #pragma unroll
  for (int r = 0; r < R; ++r) { dmin[r] = 3.4028234663852886e38f; imin[r] = 0; }

  for (int ch = 0; ch < NCHUNK; ++ch) {
    const int k0 = ch * TC;
    __syncthreads();   // also orders fnorm writes before first epilogue read
    // ---- stage codebook chunk: s_e[d][c], coalesced float4 loads ----
    #pragma unroll
    for (int i = 0; i < 8; ++i) {
      const int s  = tid + i * BLK;      // float4 slot 0..2047
      const int d  = s >> 5;
      const int c4 = (s & 31) * 4;
      const float4 v = ldg4(emb + (size_t)d * KCODES + k0 + c4);
      *reinterpret_cast<float4*>(&s_e[d * TC + c4]) = v;
    }
    __syncthreads();

    float acc[R][C];
    #pragma unroll
    for (int r = 0; r < R; ++r)
      #pragma unroll
      for (int c = 0; c < C; ++c) acc[r][c] = 0.f;

    #pragma unroll 8
    for (int d = 0; d < DIM; ++d) {
      const float4 b  = *reinterpret_cast<const float4*>(&s_e[d * TC + 4 * cg]);
      const float4 a0 = *reinterpret_cast<const float4*>(&s_x[d * XSTRIDE + 8 * rg]);
      const float4 a1 = *reinterpret_cast<const float4*>(&s_x[d * XSTRIDE + 8 * rg + 4]);
      const float av[8] = {a0.x, a0.y, a0.z, a0.w, a1.x, a1.y, a1.z, a1.w};
      const float bv[4] = {b.x, b.y, b.z, b.w};
      #pragma unroll
      for (int r = 0; r < R; ++r)
        #pragma unroll
        for (int c = 0; c < C; ++c)
          acc[r][c] = fmaf(av[r], bv[c], acc[r][c]);
    }

    // ---- epilogue: exact d = (fnorm + enorm) - 2*sim, in-thread k ascending ----
    const float4 e4 = *reinterpret_cast<const float4*>(&en[k0 + 4 * cg]);
    const float ev[4] = {e4.x, e4.y, e4.z, e4.w};
    #pragma unroll
    for (int r = 0; r < R; ++r) {
      const float fn = s_fn[8 * rg + r];
      #pragma unroll
      for (int c = 0; c < C; ++c) {
        const float di = __fsub_rn(__fadd_rn(fn, ev[c]),
                                   __fmul_rn(2.0f, acc[r][c]));
        const int k = k0 + 4 * cg + c;
        if (di < dmin[r]) { dmin[r] = di; imin[r] = k; }
      }
    }
  }

  // ---- cross-lane argmin reduce within the 32-lane row-group (first-index ties) ----
  #pragma unroll
  for (int r = 0; r < R; ++r) {
    float dv = dmin[r];
    int   iv = imin[r];
    #pragma unroll
    for (int off = 16; off >= 1; off >>= 1) {
      const float d2 = __shfl_xor(dv, off, 32);
      const int   i2 = __shfl_xor(iv, off, 32);
      if (d2 < dv || (d2 == dv && i2 < iv)) { dv = d2; iv = i2; }
    }
    imin[r] = iv;
  }

  // ---- gather winning codes, write estimator, loss partials ----
  double s1 = 0.0, s2 = 0.0;
  #pragma unroll
  for (int r = 0; r < R; ++r) {
    const int row = rowbase + 8 * rg + r;
    const int kb  = imin[r];
    const int c0  = 2 * cg, c1 = 2 * cg + 1;
    const float q0 = emb[(size_t)c0 * KCODES + kb];
    const float q1 = emb[(size_t)c1 * KCODES + kb];
    const float x0 = s_x[c0 * XSTRIDE + (8 * rg + r)];
    const float x1 = s_x[c1 * XSTRIDE + (8 * rg + r)];
    float2 qv; qv.x = q0; qv.y = q1;
    *reinterpret_cast<float2*>(&out[(size_t)row * DIM + c0]) = qv;
    const float dx0 = __fsub_rn(q0, x0);
    const float dx1 = __fsub_rn(q1, x1);
    s1 += (double)dx0 + (double)dx1;
    s2 += (double)dx0 * dx0 + (double)dx1 * dx1;
  }

  // ---- wave -> block -> global reduction ----
  #pragma unroll
  for (int off = 32; off > 0; off >>= 1) {
    s1 += __shfl_down(s1, off, 64);
    s2 += __shfl_down(s2, off, 64);
  }
  const int lane = tid & 63, wid = tid >> 6;
  if (lane == 0) { s_red[wid] = s1; s_red[4 + wid] = s2; }
  __syncthreads();
  if (tid == 0) {
    const double a = (s_red[0] + s_red[1]) + (s_red[2] + s_red[3]);
    const double b = (s_red[4] + s_red[5]) + (s_red[6] + s_red[7]);
    atomicAdd(&red[0], a);
    atomicAdd(&red[1], b);
  }
}

__global__ void vq_loss(const double* __restrict__ red, float* __restrict__ out) {
  const double inv = 1.0 / (double)((long long)NROWS * DIM);
  const double m1 = red[0] * inv;
  const double m2 = red[1] * inv;
  out[(long long)NROWS * DIM] = (float)(0.25 * m1 * m1 + m2);
}

extern "C" void kernel_launch(void* const* d_in, const int* in_sizes, int n_in,
                              void* d_out, int out_size, void* d_ws, size_t ws_size,
                              hipStream_t stream) {
  const float* x   = (const float*)d_in[0];
  const float* emb = (const float*)d_in[1];
  float* out = (float*)d_out;
  double* red = (double*)d_ws;
  float* en = (float*)((char*)d_ws + 1024);
  hipMemsetAsync(d_ws, 0, 64, stream);
  vq_enorm<<<4, BLK, 0, stream>>>(emb, en);
  vq_main<<<NBLK, BLK, 0, stream>>>(x, emb, en, out, red);
  vq_loss<<<1, 1, 0, stream>>>(red, out);
}

// Round 3
// 273.619 us; speedup vs baseline: 4.6410x; 1.8008x over previous
//
#include <hip/hip_runtime.h>

typedef _Float16 half8 __attribute__((ext_vector_type(8)));
typedef float f32x4 __attribute__((ext_vector_type(4)));

#define DIM     64
#define KCODES  4096
#define NROWS   65536
#define BLK     256
#define BM      128
#define NBLKM   (NROWS / BM)          // 512
#define BN      64
#define NCH     (KCODES / BN)         // 64
#define XS      68                    // s_x row stride (floats), 16B-aligned
#define CAP     32
#define MARGIN  1e-4f
#define SIMSCALE (-7.62939453125e-06f) // -2 / (512*512), exact pow2

// workspace byte offsets
#define WS_OVFC 64
#define WS_OVFR 128
#define WS_EN   262272
#define WS_EMBT 278656
#define WS_BH   1327232
#define WS_BL   1851520

__device__ __forceinline__ float4 ldg4(const float* p) {
  return *reinterpret_cast<const float4*>(p);
}

// ---- ||e_k||^2, numpy pairwise-8 over d (bit-validated rounds 0-1) ----
__global__ __launch_bounds__(BLK) void vq_enorm(const float* __restrict__ emb,
                                                float* __restrict__ en) {
  const int k0 = 4 * threadIdx.x + 1024 * blockIdx.x;
  float4 acc[8];
  #pragma unroll
  for (int j = 0; j < 8; ++j) {
    float4 e = ldg4(emb + j * KCODES + k0);
    acc[j].x = __fmul_rn(e.x, e.x); acc[j].y = __fmul_rn(e.y, e.y);
    acc[j].z = __fmul_rn(e.z, e.z); acc[j].w = __fmul_rn(e.w, e.w);
  }
  #pragma unroll
  for (int i = 1; i < 8; ++i) {
    #pragma unroll
    for (int j = 0; j < 8; ++j) {
      float4 e = ldg4(emb + (8 * i + j) * KCODES + k0);
      acc[j].x = __fadd_rn(acc[j].x, __fmul_rn(e.x, e.x));
      acc[j].y = __fadd_rn(acc[j].y, __fmul_rn(e.y, e.y));
      acc[j].z = __fadd_rn(acc[j].z, __fmul_rn(e.z, e.z));
      acc[j].w = __fadd_rn(acc[j].w, __fmul_rn(e.w, e.w));
    }
  }
  float4 s;
  s.x = __fadd_rn(__fadd_rn(__fadd_rn(acc[0].x, acc[1].x), __fadd_rn(acc[2].x, acc[3].x)),
                  __fadd_rn(__fadd_rn(acc[4].x, acc[5].x), __fadd_rn(acc[6].x, acc[7].x)));
  s.y = __fadd_rn(__fadd_rn(__fadd_rn(acc[0].y, acc[1].y), __fadd_rn(acc[2].y, acc[3].y)),
                  __fadd_rn(__fadd_rn(acc[4].y, acc[5].y), __fadd_rn(acc[6].y, acc[7].y)));
  s.z = __fadd_rn(__fadd_rn(__fadd_rn(acc[0].z, acc[1].z), __fadd_rn(acc[2].z, acc[3].z)),
                  __fadd_rn(__fadd_rn(acc[4].z, acc[5].z), __fadd_rn(acc[6].z, acc[7].z)));
  s.w = __fadd_rn(__fadd_rn(__fadd_rn(acc[0].w, acc[1].w), __fadd_rn(acc[2].w, acc[3].w)),
                  __fadd_rn(__fadd_rn(acc[4].w, acc[5].w), __fadd_rn(acc[6].w, acc[7].w)));
  *reinterpret_cast<float4*>(&en[k0]) = s;
}

// ---- transpose emb -> embt [4096][64] f32 + fp16 split (x512) bh/bl ----
__global__ __launch_bounds__(BLK) void prep_t(const float* __restrict__ emb,
                                              float* __restrict__ embt,
                                              _Float16* __restrict__ bh,
                                              _Float16* __restrict__ bl) {
  const int c = blockIdx.x * BLK + threadIdx.x;   // code 0..4095
  #pragma unroll
  for (int kg = 0; kg < 8; ++kg) {
    float v[8]; half8 h, l;
    #pragma unroll
    for (int j = 0; j < 8; ++j) v[j] = emb[(size_t)(kg * 8 + j) * KCODES + c];
    #pragma unroll
    for (int j = 0; j < 8; ++j) {
      const float t = v[j] * 512.0f;              // exact pow2 scale
      const _Float16 hh = (_Float16)t;
      const float rr = t - (float)hh;             // exact residual
      h[j] = hh; l[j] = (_Float16)rr;
    }
    float4 o0, o1;
    o0.x = v[0]; o0.y = v[1]; o0.z = v[2]; o0.w = v[3];
    o1.x = v[4]; o1.y = v[5]; o1.z = v[6]; o1.w = v[7];
    *reinterpret_cast<float4*>(&embt[(size_t)c * DIM + kg * 8])     = o0;
    *reinterpret_cast<float4*>(&embt[(size_t)c * DIM + kg * 8 + 4]) = o1;
    *reinterpret_cast<half8*>(&bh[(size_t)c * DIM + kg * 8]) = h;
    *reinterpret_cast<half8*>(&bl[(size_t)c * DIM + kg * 8]) = l;
  }
}

// ---- main: MFMA approx scan -> candidates -> exact f32 rescore ----
__global__ __launch_bounds__(BLK) void vq_main(
    const float* __restrict__ x, const float* __restrict__ embt,
    const _Float16* __restrict__ bh, const _Float16* __restrict__ bl,
    const float* __restrict__ en, float* __restrict__ out,
    double* __restrict__ red, int* __restrict__ ovfc, int* __restrict__ ovfr) {
  __shared__ float s_x[BM][XS];
  __shared__ _Float16 s_bh[BN * DIM];
  __shared__ _Float16 s_bl[BN * DIM];
  __shared__ float s_fn[BM];
  __shared__ unsigned s_thr[BM];
  __shared__ int s_cnt[BM];
  __shared__ unsigned short s_list[BM][CAP];
  __shared__ double s_red[8];

  const int tid = threadIdx.x;
  const int lane = tid & 63;
  const int w = tid >> 6;
  const int l15 = lane & 15;
  const int l4 = lane >> 4;
  const int rowbase = blockIdx.x * BM;

  // stage x tile (row-major, coalesced)
  #pragma unroll
  for (int i = 0; i < 8; ++i) {
    const int slot = tid + i * BLK;
    const int r = slot >> 4, c4 = (slot & 15) * 4;
    const float4 v = ldg4(x + (size_t)(rowbase + r) * DIM + c4);
    *reinterpret_cast<float4*>(&s_x[r][c4]) = v;
  }
  if (tid < BM) { s_thr[tid] = 0x7F800000u; s_cnt[tid] = 0; }
  __syncthreads();

  // fn per row (pairwise-8, round-0 op order)
  if (tid < BM) {
    float r8[8];
    #pragma unroll
    for (int j = 0; j < 8; ++j) { const float v = s_x[tid][j]; r8[j] = __fmul_rn(v, v); }
    #pragma unroll
    for (int i = 1; i < 8; ++i)
      #pragma unroll
      for (int j = 0; j < 8; ++j) {
        const float v = s_x[tid][8 * i + j];
        r8[j] = __fadd_rn(r8[j], __fmul_rn(v, v));
      }
    s_fn[tid] = __fadd_rn(
        __fadd_rn(__fadd_rn(r8[0], r8[1]), __fadd_rn(r8[2], r8[3])),
        __fadd_rn(__fadd_rn(r8[4], r8[5]), __fadd_rn(r8[6], r8[7])));
  }

  // A fragments: rows w*32 + mt*16 + l15, k = kf*32 + l4*8 + j  (x512 split)
  half8 ah[2][2], al[2][2];
  #pragma unroll
  for (int mt = 0; mt < 2; ++mt)
    #pragma unroll
    for (int kf = 0; kf < 2; ++kf) {
      const float* p = &s_x[w * 32 + mt * 16 + l15][kf * 32 + l4 * 8];
      #pragma unroll
      for (int j = 0; j < 8; ++j) {
        const float t = p[j] * 512.0f;
        const _Float16 hh = (_Float16)t;
        const float rr = t - (float)hh;
        ah[mt][kf][j] = hh; al[mt][kf][j] = (_Float16)rr;
      }
    }
  __syncthreads();

  float fnr[2][4];
  #pragma unroll
  for (int mt = 0; mt < 2; ++mt)
    #pragma unroll
    for (int r4 = 0; r4 < 4; ++r4)
      fnr[mt][r4] = s_fn[w * 32 + mt * 16 + l4 * 4 + r4];

  float rm[2][4];
  #pragma unroll
  for (int mt = 0; mt < 2; ++mt)
    #pragma unroll
    for (int r4 = 0; r4 < 4; ++r4) rm[mt][r4] = 3.4e38f;

  uint4 R[4];
  auto load_chunk = [&](int ch) {
    const char* pbh = (const char*)bh + (size_t)ch * BN * DIM * 2;
    const char* pbl = (const char*)bl + (size_t)ch * BN * DIM * 2;
    R[0] = *(const uint4*)(pbh + tid * 32);
    R[1] = *(const uint4*)(pbh + tid * 32 + 16);
    R[2] = *(const uint4*)(pbl + tid * 32);
    R[3] = *(const uint4*)(pbl + tid * 32 + 16);
  };
  auto write_chunk = [&]() {   // XOR-swizzle (T2): unit 16B, col16 ^= code&7
    #pragma unroll
    for (int j = 0; j < 2; ++j) {
      const int u = 2 * tid + j;
      const int code = u >> 3, c16 = u & 7;
      const int sw = c16 ^ (code & 7);
      *(uint4*)((char*)s_bh + code * 128 + sw * 16) = R[j];
      *(uint4*)((char*)s_bl + code * 128 + sw * 16) = R[2 + j];
    }
  };

  auto compute = [&](int ch, bool accept) {
    float thrm[2][4];
    #pragma unroll
    for (int mt = 0; mt < 2; ++mt)
      #pragma unroll
      for (int r4 = 0; r4 < 4; ++r4)
        thrm[mt][r4] = __uint_as_float(s_thr[w * 32 + mt * 16 + l4 * 4 + r4]) + MARGIN;
    #pragma unroll
    for (int nt = 0; nt < 4; ++nt) {
      const int codeL = nt * 16 + l15;
      const int gcode = ch * BN + codeL;
      const float env = en[gcode];
      half8 bhf[2], blf[2];
      #pragma unroll
      for (int kf = 0; kf < 2; ++kf) {
        const int c16 = kf * 4 + l4;
        const int off = codeL * 128 + ((c16 ^ (codeL & 7)) * 16);
        bhf[kf] = *(half8*)((char*)s_bh + off);
        blf[kf] = *(half8*)((char*)s_bl + off);
      }
      #pragma unroll
      for (int mt = 0; mt < 2; ++mt) {
        f32x4 acc = {0.f, 0.f, 0.f, 0.f};
        #pragma unroll
        for (int kf = 0; kf < 2; ++kf) {
          acc = __builtin_amdgcn_mfma_f32_16x16x32_f16(ah[mt][kf], bhf[kf], acc, 0, 0, 0);
          acc = __builtin_amdgcn_mfma_f32_16x16x32_f16(ah[mt][kf], blf[kf], acc, 0, 0, 0);
          acc = __builtin_amdgcn_mfma_f32_16x16x32_f16(al[mt][kf], bhf[kf], acc, 0, 0, 0);
        }
        #pragma unroll
        for (int r4 = 0; r4 < 4; ++r4) {
          const float dt = fmaf(acc[r4], SIMSCALE, fnr[mt][r4] + env);
          const int rloc = w * 32 + mt * 16 + l4 * 4 + r4;
          if (dt < rm[mt][r4]) {
            rm[mt][r4] = dt;
            atomicMin(&s_thr[rloc], __float_as_uint(dt));  // d > 0 => bit-order ok
          }
          if (accept && dt <= thrm[mt][r4]) {
            const int ix = atomicAdd(&s_cnt[rloc], 1);
            if (ix < CAP) s_list[rloc][ix] = (unsigned short)gcode;
          }
        }
      }
    }
  };

  // prepass: chunk 0, min-only (seeds s_thr so chunk 0 doesn't accept-all)
  load_chunk(0);
  write_chunk();
  __syncthreads();
  compute(0, false);

  // full scan with candidate collection; next-chunk prefetch into regs
  load_chunk(0);
  for (int ch = 0; ch < NCH; ++ch) {
    __syncthreads();
    write_chunk();
    __syncthreads();
    if (ch + 1 < NCH) load_chunk(ch + 1);
    compute(ch, true);
  }
  __syncthreads();

  // exact rescore (bit-identical to round-0 scoring), output, loss partials
  double s1 = 0.0, s2 = 0.0;
  if (tid < BM) {
    const int r = tid, grow = rowbase + r;
    const int cnt = s_cnt[r];
    if (cnt > CAP) {
      const int gi = atomicAdd(ovfc, 1);
      ovfr[gi] = grow;
    } else {
      float dbest = 3.4e38f; int kbest = 0x7FFFFFFF;
      const float fn = s_fn[r];
      for (int i = 0; i < cnt; ++i) {
        const int k = s_list[r][i];
        const float* ep = embt + (size_t)k * DIM;
        float dot = 0.f;
        #pragma unroll
        for (int j = 0; j < DIM / 4; ++j) {
          const float4 e4 = ldg4(ep + 4 * j);
          dot = fmaf(s_x[r][4 * j + 0], e4.x, dot);
          dot = fmaf(s_x[r][4 * j + 1], e4.y, dot);
          dot = fmaf(s_x[r][4 * j + 2], e4.z, dot);
          dot = fmaf(s_x[r][4 * j + 3], e4.w, dot);
        }
        const float d = __fsub_rn(__fadd_rn(fn, en[k]), __fmul_rn(2.0f, dot));
        if (d < dbest || (d == dbest && k < kbest)) { dbest = d; kbest = k; }
      }
      const float* qp = embt + (size_t)kbest * DIM;
      #pragma unroll
      for (int j = 0; j < 16; ++j) {
        const float4 q = ldg4(qp + 4 * j);
        *reinterpret_cast<float4*>(&out[(size_t)grow * DIM + 4 * j]) = q;
        const float d0 = __fsub_rn(q.x, s_x[r][4 * j + 0]);
        const float d1 = __fsub_rn(q.y, s_x[r][4 * j + 1]);
        const float d2 = __fsub_rn(q.z, s_x[r][4 * j + 2]);
        const float d3 = __fsub_rn(q.w, s_x[r][4 * j + 3]);
        s1 += ((double)d0 + (double)d1) + ((double)d2 + (double)d3);
        s2 += ((double)d0 * d0 + (double)d1 * d1) + ((double)d2 * d2 + (double)d3 * d3);
      }
    }
  }
  #pragma unroll
  for (int off = 32; off > 0; off >>= 1) {
    s1 += __shfl_down(s1, off, 64);
    s2 += __shfl_down(s2, off, 64);
  }
  if (lane == 0) { s_red[w] = s1; s_red[4 + w] = s2; }
  __syncthreads();
  if (tid == 0) {
    const double a = (s_red[0] + s_red[1]) + (s_red[2] + s_red[3]);
    const double b = (s_red[4] + s_red[5]) + (s_red[6] + s_red[7]);
    atomicAdd(&red[0], a);
    atomicAdd(&red[1], b);
  }
}

// ---- fallback: full exact scan for candidate-overflow rows (expected 0) ----
__global__ __launch_bounds__(BLK) void vq_fallback(
    const float* __restrict__ x, const float* __restrict__ embt,
    const float* __restrict__ en, float* __restrict__ out,
    double* __restrict__ red, const int* __restrict__ ovfc,
    const int* __restrict__ ovfr) {
  const int n = *ovfc;
  const int gw = (blockIdx.x * BLK + threadIdx.x) >> 6;
  const int lane = threadIdx.x & 63;
  const int nw = gridDim.x * (BLK / 64);
  for (int i = gw; i < n; i += nw) {
    const int row = ovfr[i];
    float f[DIM];
    #pragma unroll
    for (int j = 0; j < 16; ++j) {
      const float4 v = ldg4(x + (size_t)row * DIM + 4 * j);
      f[4 * j] = v.x; f[4 * j + 1] = v.y; f[4 * j + 2] = v.z; f[4 * j + 3] = v.w;
    }
    float r8[8];
    #pragma unroll
    for (int j = 0; j < 8; ++j) r8[j] = __fmul_rn(f[j], f[j]);
    #pragma unroll
    for (int ii = 1; ii < 8; ++ii)
      #pragma unroll
      for (int j = 0; j < 8; ++j)
        r8[j] = __fadd_rn(r8[j], __fmul_rn(f[8 * ii + j], f[8 * ii + j]));
    const float fn = __fadd_rn(
        __fadd_rn(__fadd_rn(r8[0], r8[1]), __fadd_rn(r8[2], r8[3])),
        __fadd_rn(__fadd_rn(r8[4], r8[5]), __fadd_rn(r8[6], r8[7])));
    float dbest = 3.4e38f; int kbest = 0x7FFFFFFF;
    for (int j = 0; j < KCODES / 64; ++j) {
      const int k = j * 64 + lane;            // in-lane ascending
      const float* ep = embt + (size_t)k * DIM;
      float dot = 0.f;
      #pragma unroll
      for (int jj = 0; jj < 16; ++jj) {
        const float4 e4 = ldg4(ep + 4 * jj);
        dot = fmaf(f[4 * jj], e4.x, dot);
        dot = fmaf(f[4 * jj + 1], e4.y, dot);
        dot = fmaf(f[4 * jj + 2], e4.z, dot);
        dot = fmaf(f[4 * jj + 3], e4.w, dot);
      }
      const float d = __fsub_rn(__fadd_rn(fn, en[k]), __fmul_rn(2.0f, dot));
      if (d < dbest) { dbest = d; kbest = k; }
    }
    #pragma unroll
    for (int off = 32; off > 0; off >>= 1) {
      const float d2 = __shfl_xor(dbest, off, 64);
      const int k2 = __shfl_xor(kbest, off, 64);
      if (d2 < dbest || (d2 == dbest && k2 < kbest)) { dbest = d2; kbest = k2; }
    }
    double s1 = 0.0, s2 = 0.0;
    if (lane < 16) {
      const float4 q = ldg4(embt + (size_t)kbest * DIM + lane * 4);
      *reinterpret_cast<float4*>(&out[(size_t)row * DIM + lane * 4]) = q;
      const float d0 = __fsub_rn(q.x, f[lane * 4]);
      const float d1 = __fsub_rn(q.y, f[lane * 4 + 1]);
      const float d2 = __fsub_rn(q.z, f[lane * 4 + 2]);
      const float d3 = __fsub_rn(q.w, f[lane * 4 + 3]);
      s1 = ((double)d0 + (double)d1) + ((double)d2 + (double)d3);
      s2 = ((double)d0 * d0 + (double)d1 * d1) + ((double)d2 * d2 + (double)d3 * d3);
    }
    #pragma unroll
    for (int off = 32; off > 0; off >>= 1) {
      s1 += __shfl_down(s1, off, 64);
      s2 += __shfl_down(s2, off, 64);
    }
    if (lane == 0) { atomicAdd(&red[0], s1); atomicAdd(&red[1], s2); }
  }
}

__global__ void vq_loss(const double* __restrict__ red, float* __restrict__ out) {
  const double inv = 1.0 / (double)((long long)NROWS * DIM);
  const double m1 = red[0] * inv;
  const double m2 = red[1] * inv;
  out[(long long)NROWS * DIM] = (float)(0.25 * m1 * m1 + m2);
}

extern "C" void kernel_launch(void* const* d_in, const int* in_sizes, int n_in,
                              void* d_out, int out_size, void* d_ws, size_t ws_size,
                              hipStream_t stream) {
  const float* x   = (const float*)d_in[0];
  const float* emb = (const float*)d_in[1];
  float* out = (float*)d_out;
  char* ws = (char*)d_ws;
  double*    red  = (double*)ws;
  int*       ovfc = (int*)(ws + WS_OVFC);
  int*       ovfr = (int*)(ws + WS_OVFR);
  float*     en   = (float*)(ws + WS_EN);
  float*     embt = (float*)(ws + WS_EMBT);
  _Float16*  bh   = (_Float16*)(ws + WS_BH);
  _Float16*  bl   = (_Float16*)(ws + WS_BL);
  hipMemsetAsync(d_ws, 0, 128, stream);
  vq_enorm<<<4, BLK, 0, stream>>>(emb, en);
  prep_t<<<16, BLK, 0, stream>>>(emb, embt, bh, bl);
  vq_main<<<NBLKM, BLK, 0, stream>>>(x, embt, bh, bl, en, out, red, ovfc, ovfr);
  vq_fallback<<<16, BLK, 0, stream>>>(x, embt, en, out, red, ovfc, ovfr);
  vq_loss<<<1, 1, 0, stream>>>(red, out);
}